// Round 9
// baseline (63.617 us; speedup 1.0000x reference)
//
#include <hip/hip_runtime.h>

#define NB    128           // DTW block size N
#define NCH   64            // channels
#define ROWB  256           // bytes per D row: 128 h16
#define PAIRB 32768         // bytes per pair's D matrix
#define LOG2E 1.4426950408889634f
#define LN2   0.6931471805599453f
#define LARGE 1e9f

typedef _Float16 h16;
typedef __attribute__((ext_vector_type(2))) _Float16 h16x2;
typedef __attribute__((ext_vector_type(8))) _Float16 h16x8;
typedef __attribute__((ext_vector_type(4))) float    f32x4;

static __device__ __forceinline__ float ex2(float x) {
#if __has_builtin(__builtin_amdgcn_exp2f)
    return __builtin_amdgcn_exp2f(x);
#else
    return exp2f(x);
#endif
}

static __device__ __forceinline__ float lg2(float x) {
#if __has_builtin(__builtin_amdgcn_logf)
    return __builtin_amdgcn_logf(x);   // v_log_f32 = log2
#else
    return log2f(x);
#endif
}

// lane t gets lane t-1's src; lane 0 gets `fill`. Pure VALU (DPP wave_shr:1).
static __device__ __forceinline__ float shift_up1(float src, float fill) {
    int r = __builtin_amdgcn_update_dpp(__builtin_bit_cast(int, fill),
                                        __builtin_bit_cast(int, src),
                                        0x138 /*wave_shr:1*/, 0xf, 0xf, false);
    return __builtin_bit_cast(float, r);
}

// soft-min of 3 in log2 domain + D*log2e (gamma=1, exact w.r.t. reference).
static __device__ __forceinline__ float softmin3(float a, float b, float c, float Dv) {
    float m = fminf(fminf(a, b), c);
    float M = fmaxf(fmaxf(a, b), c);
#if __has_builtin(__builtin_amdgcn_fmed3f)
    float e = __builtin_amdgcn_fmed3f(a, b, c);
#else
    float e = ((a + b) + c) - m - M;
#endif
    float s = 1.0f + (ex2(m - e) + ex2(m - M));
    return fmaf(Dv, LOG2E, m - lg2(s));
}

// BUILD: MFMA D = ||x_i||^2 + ||y_j||^2 - 2 x.y^T for one pair, into sD (LDS).
// Verbatim structure of the verified round-7 build (absmax 0.0).
#define BUILD(XP, YP) { \
    h16x8 Bf[8][2]; float y2r[8]; \
    _Pragma("unroll") \
    for (int J = 0; J < 8; ++J) { \
        const float* py = (YP) + (16 * J + c) * NCH + 8 * g; \
        float p = 0.f; \
        _Pragma("unroll") \
        for (int q = 0; q < 2; ++q) { \
            float4 a = *(const float4*)(py + 32 * q); \
            float4 bq = *(const float4*)(py + 32 * q + 4); \
            h16x8 h; \
            h[0]=(h16)a.x; h[1]=(h16)a.y; h[2]=(h16)a.z; h[3]=(h16)a.w; \
            h[4]=(h16)bq.x; h[5]=(h16)bq.y; h[6]=(h16)bq.z; h[7]=(h16)bq.w; \
            Bf[J][q] = h; \
            p = fmaf(a.x,a.x,p); p = fmaf(a.y,a.y,p); \
            p = fmaf(a.z,a.z,p); p = fmaf(a.w,a.w,p); \
            p = fmaf(bq.x,bq.x,p); p = fmaf(bq.y,bq.y,p); \
            p = fmaf(bq.z,bq.z,p); p = fmaf(bq.w,bq.w,p); \
        } \
        p += __shfl_xor(p, 16, 64); \
        p += __shfl_xor(p, 32, 64); \
        y2r[J] = p; \
    } \
    float4 nx0, nx1, nx2, nx3; \
    { \
        const float* px = (XP) + c * NCH + 8 * g; \
        nx0 = *(const float4*)(px);      nx1 = *(const float4*)(px + 4); \
        nx2 = *(const float4*)(px + 32); nx3 = *(const float4*)(px + 36); \
    } \
    for (int I = 0; I < 8; ++I) { \
        float4 a0 = nx0, a1 = nx1, a2 = nx2, a3 = nx3; \
        if (I < 7) { \
            const float* px = (XP) + (16 * (I + 1) + c) * NCH + 8 * g; \
            nx0 = *(const float4*)(px);      nx1 = *(const float4*)(px + 4); \
            nx2 = *(const float4*)(px + 32); nx3 = *(const float4*)(px + 36); \
        } \
        h16x8 Af0, Af1; \
        Af0[0]=(h16)a0.x; Af0[1]=(h16)a0.y; Af0[2]=(h16)a0.z; Af0[3]=(h16)a0.w; \
        Af0[4]=(h16)a1.x; Af0[5]=(h16)a1.y; Af0[6]=(h16)a1.z; Af0[7]=(h16)a1.w; \
        Af1[0]=(h16)a2.x; Af1[1]=(h16)a2.y; Af1[2]=(h16)a2.z; Af1[3]=(h16)a2.w; \
        Af1[4]=(h16)a3.x; Af1[5]=(h16)a3.y; Af1[6]=(h16)a3.z; Af1[7]=(h16)a3.w; \
        float p_ = 0.f; \
        p_=fmaf(a0.x,a0.x,p_); p_=fmaf(a0.y,a0.y,p_); p_=fmaf(a0.z,a0.z,p_); p_=fmaf(a0.w,a0.w,p_); \
        p_=fmaf(a1.x,a1.x,p_); p_=fmaf(a1.y,a1.y,p_); p_=fmaf(a1.z,a1.z,p_); p_=fmaf(a1.w,a1.w,p_); \
        p_=fmaf(a2.x,a2.x,p_); p_=fmaf(a2.y,a2.y,p_); p_=fmaf(a2.z,a2.z,p_); p_=fmaf(a2.w,a2.w,p_); \
        p_=fmaf(a3.x,a3.x,p_); p_=fmaf(a3.y,a3.y,p_); p_=fmaf(a3.z,a3.z,p_); p_=fmaf(a3.w,a3.w,p_); \
        p_ += __shfl_xor(p_, 16, 64); \
        p_ += __shfl_xor(p_, 32, 64); \
        float xa_[4]; \
        xa_[0] = __shfl(p_, 4 * g + 0, 64); \
        xa_[1] = __shfl(p_, 4 * g + 1, 64); \
        xa_[2] = __shfl(p_, 4 * g + 2, 64); \
        xa_[3] = __shfl(p_, 4 * g + 3, 64); \
        f32x4 acc_[8]; \
        _Pragma("unroll") \
        for (int J = 0; J < 8; ++J) { \
            f32x4 z = {0.f, 0.f, 0.f, 0.f}; \
            z = __builtin_amdgcn_mfma_f32_16x16x32_f16(Af0, Bf[J][0], z, 0, 0, 0); \
            z = __builtin_amdgcn_mfma_f32_16x16x32_f16(Af1, Bf[J][1], z, 0, 0, 0); \
            acc_[J] = z; \
        } \
        _Pragma("unroll") \
        for (int J = 0; J < 8; ++J) { \
            char* base_ = sDb + 2 * (16 * J + c) + ROWB * (16 * I + 4 * g); \
            float y2v_ = y2r[J]; \
            _Pragma("unroll") \
            for (int r = 0; r < 4; ++r) { \
                float dv_ = fmaf(-2.0f, acc_[J][r], xa_[r] + y2v_); \
                *(h16*)(base_ + ROWB * r) = (h16)dv_; \
            } \
        } \
    } }

// ============================================================================
// Dual-pair kernel: one wave = 2 block-pairs, 2 interleaved DP chains.
// Pair1 D built in LDS then streamed to ws; pair0 D built in LDS and kept.
// DP chain0 reads LDS, chain1 reads global (L2-hot) — independent streams
// fill each other's latency bubbles (the 1-wave/SIMD latency is the wall).
// ============================================================================
__global__ __launch_bounds__(64, 1)
void dtw2(const float* __restrict__ X, const float* __restrict__ Y,
          h16* __restrict__ Dws, float* __restrict__ out, int nbpb)
{
    __shared__ h16 sD[NB * (ROWB / 2)];     // 32768 B

    const int b = blockIdx.x;               // dual-pair id
    const int w0 = 2 * b, w1 = 2 * b + 1;
    const int t = threadIdx.x;              // 0..63
    const int c = t & 15, g = t >> 4;
    char* sDb = (char*)sD;

    // ---- build pair1 -> LDS -> stream to ws (coalesced 1KB per instr)
    BUILD(X + (size_t)w1 * (NB * NCH), Y + (size_t)w1 * (NB * NCH))
    {
        char* dst = (char*)Dws + (size_t)b * PAIRB;
        #pragma unroll
        for (int u = 0; u < 32; ++u)
            *(uint4*)(dst + 1024 * u + 16 * t) =
                *(const uint4*)(sDb + 1024 * u + 16 * t);
    }
    // ---- build pair0 -> LDS (stays). Hides the store latency above.
    BUILD(X + (size_t)w0 * (NB * NCH), Y + (size_t)w0 * (NB * NCH))

    // all vmem (incl. ws stores) complete before DP reads ws
    asm volatile("s_waitcnt vmcnt(0)" ::: "memory");

    // ---- dual DP. Window logic verbatim from verified round-7/8 kernels.
    const int baseA = 508 * t;          // row 2t byte base (512t) minus 4t
    const int baseB = 508 * t + 256;
    const char* P1 = (const char*)Dws + (size_t)b * PAIRB;

    h16x2    nA0[8], nB0[8], pA0[8], pB0[8];
    unsigned nA1[8], nB1[8], pA1[8], pB1[8];

    #define LOAD8L(dst, off) { \
        const h16x2* q_ = (const h16x2*)(sDb + (off)); \
        _Pragma("unroll") for (int q = 0; q < 8; ++q) (dst)[q] = q_[q]; }
    #define LOAD8G(dst, off) { \
        _Pragma("unroll") for (int q = 0; q < 8; ++q) \
            (dst)[q] = *(const unsigned*)(P1 + (off) + 4 * q); }

    LOAD8L(nA0, baseA) LOAD8L(nB0, baseB)
    LOAD8G(nA1, baseA) LOAD8G(nB1, baseB)

    float fA0[16], fB0[16], fA1[16], fB1[16];
    float r1a0 = LARGE, r1b0 = LARGE, r2a0 = LARGE;
    float r1a1 = LARGE, r1b1 = LARGE, r2a1 = LARGE;
    float dgp0 = (t == 0) ? 0.0f : LARGE;   // corner R[-1][-1]=0
    float dgp1 = (t == 0) ? 0.0f : LARGE;
    float cB0 = 0.0f, cB1 = 0.0f;

    #define CVT0(sa, sb) { _Pragma("unroll") for (int q = 0; q < 8; ++q) { \
        fA0[2*q] = (float)(sa)[q][0]; fA0[2*q+1] = (float)(sa)[q][1]; \
        fB0[2*q] = (float)(sb)[q][0]; fB0[2*q+1] = (float)(sb)[q][1]; } }
    #define CVT1(sa, sb) { _Pragma("unroll") for (int q = 0; q < 8; ++q) { \
        h16x2 va = __builtin_bit_cast(h16x2, (sa)[q]); \
        h16x2 vb = __builtin_bit_cast(h16x2, (sb)[q]); \
        fA1[2*q] = (float)va[0]; fA1[2*q+1] = (float)va[1]; \
        fB1[2*q] = (float)vb[0]; fB1[2*q+1] = (float)vb[1]; } }

    #define STEPP(r1a, r1b, r2a, dgp, D0v, D1v) { \
        float up_ = shift_up1(r1b, LARGE); \
        float n0_ = softmin3(r1a, up_, dgp, (D0v)); \
        float n1_ = softmin3(r1b, r1a, r2a, (D1v)); \
        r2a = r1a; r1a = n0_; r1b = n1_; dgp = up_; }

    #define BODY(cA0_, cB0_, xA0_, xB0_, cA1_, cB1_, xA1_, xB1_, ccv) { \
        if ((ccv) < 15) { \
            LOAD8L(xA0_, baseA + 32 * ((ccv) + 1)) \
            LOAD8L(xB0_, baseB + 32 * ((ccv) + 1)) \
            LOAD8G(xA1_, baseA + 32 * ((ccv) + 1)) \
            LOAD8G(xB1_, baseB + 32 * ((ccv) + 1)) \
        } \
        CVT0(cA0_, cB0_) \
        CVT1(cA1_, cB1_) \
        const int kmax = ((ccv) == 15) ? 15 : 16; \
        _Pragma("unroll") \
        for (int k = 0; k < 16; ++k) { \
            if (k < kmax) { \
                float D1v0 = (k == 0) ? cB0 : fB0[k - 1]; \
                STEPP(r1a0, r1b0, r2a0, dgp0, fA0[k], D1v0) \
                float D1v1 = (k == 0) ? cB1 : fB1[k - 1]; \
                STEPP(r1a1, r1b1, r2a1, dgp1, fA1[k], D1v1) \
            } \
        } \
        cB0 = fB0[15]; cB1 = fB1[15]; }

    #pragma unroll
    for (int cc = 0; cc < 16; cc += 2) {
        BODY(nA0, nB0, pA0, pB0, nA1, nB1, pA1, pB1, cc)
        BODY(pA0, pB0, nA0, nB0, pA1, pB1, nA1, nB1, cc + 1)
    }

    if (t == 63) {
        atomicAdd(&out[w0 / nbpb], r1b0 * LN2);
        atomicAdd(&out[w1 / nbpb], r1b1 * LN2);
    }
}

// ============================================================================
// Fallback: verified round-7 fused single-pair kernel (ws too small / odd nblk)
// ============================================================================
__global__ __launch_bounds__(64, 1)
void dtw_k(const float* __restrict__ X, const float* __restrict__ Y,
           float* __restrict__ out, int nbpb)
{
    __shared__ h16 sD[NB * (ROWB / 2)];

    const int w = blockIdx.x;
    const int t = threadIdx.x;
    const int c = t & 15, g = t >> 4;
    char* sDb = (char*)sD;
    const float* gx = X + (size_t)w * (NB * NCH);
    const float* gy = Y + (size_t)w * (NB * NCH);

    {
        uint4 zz = {0u, 0u, 0u, 0u};
        #pragma unroll
        for (int i = 0; i < 32; ++i)
            *(uint4*)(sDb + 1024 * i + 16 * t) = zz;
    }

    BUILD(gx, gy)

    const int baseA = 508 * t;
    const int baseB = 508 * t + 256;

    h16x2 nA[8], nB[8];
    #define FT_LOAD8(dst, off) { \
        const h16x2* p_ = (const h16x2*)(sDb + (off)); \
        _Pragma("unroll") for (int q = 0; q < 8; ++q) (dst)[q] = p_[q]; }

    FT_LOAD8(nA, baseA)
    FT_LOAD8(nB, baseB)

    float fA[16], fB[16];
    float r1a = LARGE, r1b = LARGE, r2a = LARGE;
    float dgp = (t == 0) ? 0.0f : LARGE;
    float carryB = 0.0f;

    #define FT_CVT() { _Pragma("unroll") for (int q = 0; q < 8; ++q) { \
        fA[2*q] = (float)nA[q][0]; fA[2*q+1] = (float)nA[q][1]; \
        fB[2*q] = (float)nB[q][0]; fB[2*q+1] = (float)nB[q][1]; } }

    for (int cc = 0; cc < 15; ++cc) {
        FT_CVT()
        FT_LOAD8(nA, baseA + 32 * (cc + 1))
        FT_LOAD8(nB, baseB + 32 * (cc + 1))
        #pragma unroll
        for (int k = 0; k < 16; ++k) {
            float D1v = (k == 0) ? carryB : fB[k - 1];
            STEPP(r1a, r1b, r2a, dgp, fA[k], D1v)
        }
        carryB = fB[15];
    }
    FT_CVT()
    #pragma unroll
    for (int k = 0; k < 15; ++k) {
        float D1v = (k == 0) ? carryB : fB[k - 1];
        STEPP(r1a, r1b, r2a, dgp, fA[k], D1v)
    }

    if (t == 63) {
        atomicAdd(&out[w / nbpb], r1b * LN2);
    }
}

extern "C" void kernel_launch(void* const* d_in, const int* in_sizes, int n_in,
                              void* d_out, int out_size, void* d_ws, size_t ws_size,
                              hipStream_t stream) {
    const float* x = (const float*)d_in[0];
    const float* y = (const float*)d_in[1];
    float* out = (float*)d_out;

    const int nblk = in_sizes[0] / (NB * NCH);   // 1024 block-pairs
    const int nbpb = nblk / out_size;            // 32 blocks per batch

    hipMemsetAsync(out, 0, (size_t)out_size * sizeof(float), stream);

    if ((nblk % 2 == 0) && ws_size >= (size_t)(nblk / 2) * PAIRB) {
        dtw2<<<nblk / 2, 64, 0, stream>>>(x, y, (h16*)d_ws, out, nbpb);
    } else {
        dtw_k<<<nblk, 64, 0, stream>>>(x, y, out, nbpb);
    }
}

// Round 10
// 50.800 us; speedup vs baseline: 1.2523x; 1.2523x over previous
//
#include <hip/hip_runtime.h>

#define NB    128           // DTW block size N
#define NCH   64            // channels
#define ROWB  256           // bytes per sD row: 128 h16, NO pad (fits 32 KiB)
#define LOG2E 1.4426950408889634f
#define LN2   0.6931471805599453f
#define LARGE 1e9f

typedef _Float16 h16;
typedef __attribute__((ext_vector_type(2))) _Float16 h16x2;
typedef __attribute__((ext_vector_type(8))) _Float16 h16x8;
typedef __attribute__((ext_vector_type(4))) float    f32x4;

// PWL (max-of-tangents) approx of g(d) = log2(1 + 2^-d), d >= 0.
// Convex decreasing => max of tangent lines under-estimates by <= 0.023.
// All full-rate VALU (FMA + max3) — removes exp/log from the DP chain.
static __device__ __forceinline__ float gcorr(float d) {
    float t1 = fmaf(d, -0.50000000f, 1.00000000f);   // tangent at 0
    float t2 = fmaf(d, -0.33333333f, 0.91830075f);   // at 1
    float t3 = fmaf(d, -0.17874438f, 0.67729753f);   // at 2.2
    float t4 = fmaf(d, -0.06696601f, 0.35448527f);   // at 3.8
    float t5 = fmaf(d, -0.01538462f, 0.11467551f);   // at 6
    float a = fmaxf(fmaxf(t1, t2), t3);              // v_max3
    float b = fmaxf(fmaxf(t4, t5), 0.0f);            // v_max3 (0-line: d->inf)
    return fmaxf(a, b);
}

// soft-min of 3 in log2 domain + D*log2e (gamma=1).
// Exact: m - log2(1+2^(m-e)+2^(m-M)). Approx: m - [g(e-m)+g(M-m)], PWL g.
// |err| <= ~0.03 log2-units/cell (+0.415 only at exact 3-way ties) —
// ~170 absolute on the batch output vs threshold 1.03e4.
static __device__ __forceinline__ float softmin3(float a, float b, float c, float Dv) {
    float m = fminf(fminf(a, b), c);
    float M = fmaxf(fmaxf(a, b), c);
#if __has_builtin(__builtin_amdgcn_fmed3f)
    float e = __builtin_amdgcn_fmed3f(a, b, c);
#else
    float e = ((a + b) + c) - m - M;
#endif
    float corr = gcorr(e - m) + gcorr(M - m);
    return fmaf(Dv, LOG2E, m - corr);
}

// lane t gets lane t-1's src; lane 0 gets `fill`. Pure VALU (DPP wave_shr:1).
static __device__ __forceinline__ float shift_up1(float src, float fill) {
    int r = __builtin_amdgcn_update_dpp(__builtin_bit_cast(int, fill),
                                        __builtin_bit_cast(int, src),
                                        0x138 /*wave_shr:1*/, 0xf, 0xf, false);
    return __builtin_bit_cast(float, r);
}

__global__ __launch_bounds__(64, 1)
void dtw_k(const float* __restrict__ X, const float* __restrict__ Y,
           float* __restrict__ out, int nbpb)
{
    __shared__ h16 sD[NB * (ROWB / 2)];     // 32768 B

    const int w = blockIdx.x;               // block-pair id
    const int t = threadIdx.x;              // 0..63
    const int c = t & 15, g = t >> 4;       // MFMA fragment coords
    char* sDb = (char*)sD;
    const float* gx = X + (size_t)w * (NB * NCH);
    const float* gy = Y + (size_t)w * (NB * NCH);

    // ---- zero-fill sD: fused schedule reads not-yet-written rows out-of-window;
    // init 0 keeps every junk read finite >= 0 (round-4 lesson).
    {
        uint4 zz = {0u, 0u, 0u, 0u};
        #pragma unroll
        for (int i = 0; i < 32; ++i)
            *(uint4*)(sDb + 1024 * i + 16 * t) = zz;   // 32 KiB exactly
    }

    // ---- B fragments (y rows as MFMA B operand) + y2 norms, all in registers.
    h16x8 Bf[8][2];
    float y2r[8];
    #pragma unroll
    for (int J = 0; J < 8; ++J) {
        const float* py = gy + (16 * J + c) * NCH + 8 * g;
        float p = 0.f;
        #pragma unroll
        for (int q = 0; q < 2; ++q) {
            float4 a = *(const float4*)(py + 32 * q);
            float4 b = *(const float4*)(py + 32 * q + 4);
            h16x8 h;
            h[0]=(h16)a.x; h[1]=(h16)a.y; h[2]=(h16)a.z; h[3]=(h16)a.w;
            h[4]=(h16)b.x; h[5]=(h16)b.y; h[6]=(h16)b.z; h[7]=(h16)b.w;
            Bf[J][q] = h;
            p = fmaf(a.x,a.x,p); p = fmaf(a.y,a.y,p);
            p = fmaf(a.z,a.z,p); p = fmaf(a.w,a.w,p);
            p = fmaf(b.x,b.x,p); p = fmaf(b.y,b.y,p);
            p = fmaf(b.z,b.z,p); p = fmaf(b.w,b.w,p);
        }
        p += __shfl_xor(p, 16, 64);
        p += __shfl_xor(p, 32, 64);
        y2r[J] = p;                          // ||y[16J+c]||^2
    }

    // ---- A-fragment prefetch registers (tile I data lives in nx before TILE(I))
    float4 nx0, nx1, nx2, nx3;
    {
        const float* px = gx + c * NCH + 8 * g;
        nx0 = *(const float4*)(px);
        nx1 = *(const float4*)(px + 4);
        nx2 = *(const float4*)(px + 32);
        nx3 = *(const float4*)(px + 36);
    }

    // TILE(I): consume nx -> A frags + x2; prefetch tile I+1; 16 MFMAs; D epilogue.
    #define TILE(Iexp) { \
        const int I_ = (Iexp); \
        float4 a0 = nx0, a1 = nx1, a2 = nx2, a3 = nx3; \
        if (I_ < 7) { \
            const float* px = gx + (16 * (I_ + 1) + c) * NCH + 8 * g; \
            nx0 = *(const float4*)(px); \
            nx1 = *(const float4*)(px + 4); \
            nx2 = *(const float4*)(px + 32); \
            nx3 = *(const float4*)(px + 36); \
        } \
        h16x8 Af0, Af1; \
        Af0[0]=(h16)a0.x; Af0[1]=(h16)a0.y; Af0[2]=(h16)a0.z; Af0[3]=(h16)a0.w; \
        Af0[4]=(h16)a1.x; Af0[5]=(h16)a1.y; Af0[6]=(h16)a1.z; Af0[7]=(h16)a1.w; \
        Af1[0]=(h16)a2.x; Af1[1]=(h16)a2.y; Af1[2]=(h16)a2.z; Af1[3]=(h16)a2.w; \
        Af1[4]=(h16)a3.x; Af1[5]=(h16)a3.y; Af1[6]=(h16)a3.z; Af1[7]=(h16)a3.w; \
        float p_ = 0.f; \
        p_=fmaf(a0.x,a0.x,p_); p_=fmaf(a0.y,a0.y,p_); p_=fmaf(a0.z,a0.z,p_); p_=fmaf(a0.w,a0.w,p_); \
        p_=fmaf(a1.x,a1.x,p_); p_=fmaf(a1.y,a1.y,p_); p_=fmaf(a1.z,a1.z,p_); p_=fmaf(a1.w,a1.w,p_); \
        p_=fmaf(a2.x,a2.x,p_); p_=fmaf(a2.y,a2.y,p_); p_=fmaf(a2.z,a2.z,p_); p_=fmaf(a2.w,a2.w,p_); \
        p_=fmaf(a3.x,a3.x,p_); p_=fmaf(a3.y,a3.y,p_); p_=fmaf(a3.z,a3.z,p_); p_=fmaf(a3.w,a3.w,p_); \
        p_ += __shfl_xor(p_, 16, 64); \
        p_ += __shfl_xor(p_, 32, 64); \
        float xa_[4]; \
        xa_[0] = __shfl(p_, 4 * g + 0, 64); \
        xa_[1] = __shfl(p_, 4 * g + 1, 64); \
        xa_[2] = __shfl(p_, 4 * g + 2, 64); \
        xa_[3] = __shfl(p_, 4 * g + 3, 64); \
        f32x4 acc_[8]; \
        _Pragma("unroll") \
        for (int J = 0; J < 8; ++J) { \
            f32x4 z = {0.f, 0.f, 0.f, 0.f}; \
            z = __builtin_amdgcn_mfma_f32_16x16x32_f16(Af0, Bf[J][0], z, 0, 0, 0); \
            z = __builtin_amdgcn_mfma_f32_16x16x32_f16(Af1, Bf[J][1], z, 0, 0, 0); \
            acc_[J] = z; \
        } \
        _Pragma("unroll") \
        for (int J = 0; J < 8; ++J) { \
            char* base_ = sDb + 2 * (16 * J + c) + ROWB * (16 * I_ + 4 * g); \
            float y2v_ = y2r[J]; \
            _Pragma("unroll") \
            for (int r = 0; r < 4; ++r) { \
                float dv_ = fmaf(-2.0f, acc_[J][r], xa_[r] + y2v_); \
                *(h16*)(base_ + ROWB * r) = (h16)dv_; \
            } \
        } }

    // ---- prologue: tile 0 must exist before DP chunk 0
    TILE(0)

    // ---- DP state & helpers (negative-offset window trick, lane t owns rows 2t/2t+1)
    const int baseA = 508 * t;          // row 2t byte base (512t) minus 4t (window shift)
    const int baseB = 508 * t + 256;

    h16x2 nA[8], nB[8];
    #define LOAD8(dst, off) { \
        const h16x2* p_ = (const h16x2*)(sDb + (off)); \
        _Pragma("unroll") for (int q = 0; q < 8; ++q) (dst)[q] = p_[q]; }

    LOAD8(nA, baseA)
    LOAD8(nB, baseB)

    float fA[16], fB[16];
    float r1a = LARGE, r1b = LARGE, r2a = LARGE;
    float dg_prev = (t == 0) ? 0.0f : LARGE;   // corner R[-1][-1]=0 feeds cell (0,0)
    float carryB = 0.0f;

    #define CONVERT() { _Pragma("unroll") for (int q = 0; q < 8; ++q) { \
        fA[2*q] = (float)nA[q][0]; fA[2*q+1] = (float)nA[q][1]; \
        fB[2*q] = (float)nB[q][0]; fB[2*q+1] = (float)nB[q][1]; } }

    #define STEP(D0v, D1v) { \
        float up_cur = shift_up1(r1b, LARGE); \
        float n0 = softmin3(r1a, up_cur, dg_prev, (D0v)); \
        float n1 = softmin3(r1b, r1a, r2a, (D1v)); \
        r2a = r1a; r1a = n0; r1b = n1; dg_prev = up_cur; }

    // ---- fused main loop: DP chunk cc + D-tile cc+1 (tiles 1..7 under chunks 0..6)
    for (int cc = 0; cc < 15; ++cc) {
        CONVERT()                       // chunk cc data -> f32 regs
        if (cc < 7) TILE(cc + 1)        // independent MFMA/pack stream fills DP bubbles
        LOAD8(nA, baseA + 32 * (cc + 1))   // after tile writes: same-wave DS is in-order
        LOAD8(nB, baseB + 32 * (cc + 1))
        #pragma unroll
        for (int k = 0; k < 16; ++k) {
            float D1v = (k == 0) ? carryB : fB[k - 1];
            STEP(fA[k], D1v)
        }
        carryB = fB[15];
    }
    CONVERT()
    #pragma unroll
    for (int k = 0; k < 15; ++k) {      // d = 240..254; lane63 r1b ends as R~[127][127]
        float D1v = (k == 0) ? carryB : fB[k - 1];
        STEP(fA[k], D1v)
    }

    if (t == 63) {
        atomicAdd(&out[w / nbpb], r1b * LN2);   // back to natural-log domain
    }
}

extern "C" void kernel_launch(void* const* d_in, const int* in_sizes, int n_in,
                              void* d_out, int out_size, void* d_ws, size_t ws_size,
                              hipStream_t stream) {
    const float* x = (const float*)d_in[0];
    const float* y = (const float*)d_in[1];
    float* out = (float*)d_out;

    const int nblk = in_sizes[0] / (NB * NCH);   // 1024 block-pairs
    const int nbpb = nblk / out_size;            // 32 blocks per batch

    hipMemsetAsync(out, 0, (size_t)out_size * sizeof(float), stream);
    dtw_k<<<nblk, 64, 0, stream>>>(x, y, out, nbpb);
}

// Round 11
// 45.956 us; speedup vs baseline: 1.3843x; 1.1054x over previous
//
#include <hip/hip_runtime.h>

#define NB    128           // DTW block size N
#define NCH   64            // channels
#define ROWB  128           // bytes per sD row: 128 u8 cells (linear quant, step 2.0)
#define LOG2E 1.4426950408889634f
#define DKQ   2.8853900817779268f   // 2 * LOG2E: decode (x2) folded into D*log2e FMA
#define LN2   0.6931471805599453f
#define LARGE 1e9f

typedef _Float16 h16;
typedef __attribute__((ext_vector_type(8))) _Float16 h16x8;
typedef __attribute__((ext_vector_type(4))) float    f32x4;

static __device__ __forceinline__ float ex2(float x) {
#if __has_builtin(__builtin_amdgcn_exp2f)
    return __builtin_amdgcn_exp2f(x);
#else
    return exp2f(x);
#endif
}

static __device__ __forceinline__ float lg2(float x) {
#if __has_builtin(__builtin_amdgcn_logf)
    return __builtin_amdgcn_logf(x);   // v_log_f32 = log2
#else
    return log2f(x);
#endif
}

// lane t gets lane t-1's src; lane 0 gets `fill`. Pure VALU (DPP wave_shr:1).
static __device__ __forceinline__ float shift_up1(float src, float fill) {
    int r = __builtin_amdgcn_update_dpp(__builtin_bit_cast(int, fill),
                                        __builtin_bit_cast(int, src),
                                        0x138 /*wave_shr:1*/, 0xf, 0xf, false);
    return __builtin_bit_cast(float, r);
}

// soft-min of 3 in log2 domain + Dq*(2*log2e); Dq is the raw u8 byte (D/2).
// Exact trans version (round-10 showed PWL is slower: DP is issue-bound).
static __device__ __forceinline__ float softmin3(float a, float b, float c, float Dq) {
    float m = fminf(fminf(a, b), c);
    float M = fmaxf(fmaxf(a, b), c);
#if __has_builtin(__builtin_amdgcn_fmed3f)
    float e = __builtin_amdgcn_fmed3f(a, b, c);
#else
    float e = ((a + b) + c) - m - M;
#endif
    float s = 1.0f + (ex2(m - e) + ex2(m - M));
    return fmaf(Dq, DKQ, m - lg2(s));
}

__global__ __launch_bounds__(64, 1)
void dtw_k(const float* __restrict__ X, const float* __restrict__ Y,
           float* __restrict__ out, int nbpb)
{
    __shared__ unsigned char sD[NB * ROWB];   // 16384 B -> >=4 wg/CU guaranteed

    const int w = blockIdx.x;               // block-pair id
    const int t = threadIdx.x;              // 0..63
    const int c = t & 15, g = t >> 4;       // MFMA fragment coords
    char* sDb = (char*)sD;
    const float* gx = X + (size_t)w * (NB * NCH);
    const float* gy = Y + (size_t)w * (NB * NCH);

    // ---- zero-fill sD (16 KiB): fused schedule reads not-yet-written rows
    // out-of-window; byte 0 decodes to D=0 (finite >= 0) -> containment holds.
    {
        uint4 zz = {0u, 0u, 0u, 0u};
        #pragma unroll
        for (int i = 0; i < 16; ++i)
            *(uint4*)(sDb + 1024 * i + 16 * t) = zz;
    }

    // ---- B fragments (y rows as MFMA B operand) + y2 norms, all in registers.
    h16x8 Bf[8][2];
    float y2r[8];
    #pragma unroll
    for (int J = 0; J < 8; ++J) {
        const float* py = gy + (16 * J + c) * NCH + 8 * g;
        float p = 0.f;
        #pragma unroll
        for (int q = 0; q < 2; ++q) {
            float4 a = *(const float4*)(py + 32 * q);
            float4 b = *(const float4*)(py + 32 * q + 4);
            h16x8 h;
            h[0]=(h16)a.x; h[1]=(h16)a.y; h[2]=(h16)a.z; h[3]=(h16)a.w;
            h[4]=(h16)b.x; h[5]=(h16)b.y; h[6]=(h16)b.z; h[7]=(h16)b.w;
            Bf[J][q] = h;
            p = fmaf(a.x,a.x,p); p = fmaf(a.y,a.y,p);
            p = fmaf(a.z,a.z,p); p = fmaf(a.w,a.w,p);
            p = fmaf(b.x,b.x,p); p = fmaf(b.y,b.y,p);
            p = fmaf(b.z,b.z,p); p = fmaf(b.w,b.w,p);
        }
        p += __shfl_xor(p, 16, 64);
        p += __shfl_xor(p, 32, 64);
        y2r[J] = p;                          // ||y[16J+c]||^2
    }

    // ---- A-fragment prefetch registers (tile I data lives in nx before TILE(I))
    float4 nx0, nx1, nx2, nx3;
    {
        const float* px = gx + c * NCH + 8 * g;
        nx0 = *(const float4*)(px);
        nx1 = *(const float4*)(px + 4);
        nx2 = *(const float4*)(px + 32);
        nx3 = *(const float4*)(px + 36);
    }

    // TILE(I): consume nx -> A frags + x2; prefetch tile I+1; 16 MFMAs;
    // epilogue quantizes D to u8 (byte = round(D/2), clamp 255).
    #define TILE(Iexp) { \
        const int I_ = (Iexp); \
        float4 a0 = nx0, a1 = nx1, a2 = nx2, a3 = nx3; \
        if (I_ < 7) { \
            const float* px = gx + (16 * (I_ + 1) + c) * NCH + 8 * g; \
            nx0 = *(const float4*)(px); \
            nx1 = *(const float4*)(px + 4); \
            nx2 = *(const float4*)(px + 32); \
            nx3 = *(const float4*)(px + 36); \
        } \
        h16x8 Af0, Af1; \
        Af0[0]=(h16)a0.x; Af0[1]=(h16)a0.y; Af0[2]=(h16)a0.z; Af0[3]=(h16)a0.w; \
        Af0[4]=(h16)a1.x; Af0[5]=(h16)a1.y; Af0[6]=(h16)a1.z; Af0[7]=(h16)a1.w; \
        Af1[0]=(h16)a2.x; Af1[1]=(h16)a2.y; Af1[2]=(h16)a2.z; Af1[3]=(h16)a2.w; \
        Af1[4]=(h16)a3.x; Af1[5]=(h16)a3.y; Af1[6]=(h16)a3.z; Af1[7]=(h16)a3.w; \
        float p_ = 0.f; \
        p_=fmaf(a0.x,a0.x,p_); p_=fmaf(a0.y,a0.y,p_); p_=fmaf(a0.z,a0.z,p_); p_=fmaf(a0.w,a0.w,p_); \
        p_=fmaf(a1.x,a1.x,p_); p_=fmaf(a1.y,a1.y,p_); p_=fmaf(a1.z,a1.z,p_); p_=fmaf(a1.w,a1.w,p_); \
        p_=fmaf(a2.x,a2.x,p_); p_=fmaf(a2.y,a2.y,p_); p_=fmaf(a2.z,a2.z,p_); p_=fmaf(a2.w,a2.w,p_); \
        p_=fmaf(a3.x,a3.x,p_); p_=fmaf(a3.y,a3.y,p_); p_=fmaf(a3.z,a3.z,p_); p_=fmaf(a3.w,a3.w,p_); \
        p_ += __shfl_xor(p_, 16, 64); \
        p_ += __shfl_xor(p_, 32, 64); \
        float xa_[4]; \
        xa_[0] = __shfl(p_, 4 * g + 0, 64); \
        xa_[1] = __shfl(p_, 4 * g + 1, 64); \
        xa_[2] = __shfl(p_, 4 * g + 2, 64); \
        xa_[3] = __shfl(p_, 4 * g + 3, 64); \
        f32x4 acc_[8]; \
        _Pragma("unroll") \
        for (int J = 0; J < 8; ++J) { \
            f32x4 z = {0.f, 0.f, 0.f, 0.f}; \
            z = __builtin_amdgcn_mfma_f32_16x16x32_f16(Af0, Bf[J][0], z, 0, 0, 0); \
            z = __builtin_amdgcn_mfma_f32_16x16x32_f16(Af1, Bf[J][1], z, 0, 0, 0); \
            acc_[J] = z; \
        } \
        _Pragma("unroll") \
        for (int J = 0; J < 8; ++J) { \
            char* base_ = sDb + (16 * J + c) + ROWB * (16 * I_ + 4 * g); \
            float y2v_ = y2r[J]; \
            _Pragma("unroll") \
            for (int r = 0; r < 4; ++r) { \
                float dv_ = fmaf(-2.0f, acc_[J][r], xa_[r] + y2v_); \
                unsigned u_ = (unsigned)fmaf(dv_, 0.5f, 0.5f); \
                u_ = u_ > 255u ? 255u : u_; \
                *(unsigned char*)(base_ + ROWB * r) = (unsigned char)u_; \
            } \
        } }

    // ---- prologue: tile 0 must exist before DP chunk 0
    TILE(0)

    // ---- DP state (negative-offset window trick, lane t owns rows 2t/2t+1)
    // 1 B/col now: row 2t at byte 256t, col shift -2t -> baseA = 254t.
    const int baseA = 254 * t;
    const int baseB = 254 * t + 128;

    unsigned wA[8], wB[8];
    #define LOADW(dst, off) { \
        _Pragma("unroll") for (int q = 0; q < 8; ++q) \
            (dst)[q] = (unsigned)*(const unsigned short*)(sDb + (off) + 2 * q); }

    LOADW(wA, baseA)
    LOADW(wB, baseB)

    float fA[16], fB[16];
    float r1a = LARGE, r1b = LARGE, r2a = LARGE;
    float dg_prev = (t == 0) ? 0.0f : LARGE;   // corner R[-1][-1]=0 feeds cell (0,0)
    float carryB = 0.0f;

    // decode: raw byte (D/2); the x2 is folded into softmin3's DKQ constant
    #define CONVERT() { _Pragma("unroll") for (int q = 0; q < 8; ++q) { \
        fA[2*q] = (float)(wA[q] & 0xffu); fA[2*q+1] = (float)(wA[q] >> 8); \
        fB[2*q] = (float)(wB[q] & 0xffu); fB[2*q+1] = (float)(wB[q] >> 8); } }

    #define STEP(D0v, D1v) { \
        float up_cur = shift_up1(r1b, LARGE); \
        float n0 = softmin3(r1a, up_cur, dg_prev, (D0v)); \
        float n1 = softmin3(r1b, r1a, r2a, (D1v)); \
        r2a = r1a; r1a = n0; r1b = n1; dg_prev = up_cur; }

    // ---- fused main loop: DP chunk cc + D-tile cc+1 (tiles 1..7 under chunks 0..6)
    for (int cc = 0; cc < 15; ++cc) {
        CONVERT()                       // chunk cc data -> f32 regs
        if (cc < 7) TILE(cc + 1)        // independent MFMA/pack stream fills DP bubbles
        LOADW(wA, baseA + 16 * (cc + 1))   // after tile writes: same-wave DS is in-order
        LOADW(wB, baseB + 16 * (cc + 1))
        #pragma unroll
        for (int k = 0; k < 16; ++k) {
            float D1v = (k == 0) ? carryB : fB[k - 1];
            STEP(fA[k], D1v)
        }
        carryB = fB[15];
    }
    CONVERT()
    #pragma unroll
    for (int k = 0; k < 15; ++k) {      // d = 240..254; lane63 r1b ends as R~[127][127]
        float D1v = (k == 0) ? carryB : fB[k - 1];
        STEP(fA[k], D1v)
    }

    if (t == 63) {
        atomicAdd(&out[w / nbpb], r1b * LN2);   // back to natural-log domain
    }
}

extern "C" void kernel_launch(void* const* d_in, const int* in_sizes, int n_in,
                              void* d_out, int out_size, void* d_ws, size_t ws_size,
                              hipStream_t stream) {
    const float* x = (const float*)d_in[0];
    const float* y = (const float*)d_in[1];
    float* out = (float*)d_out;

    const int nblk = in_sizes[0] / (NB * NCH);   // 1024 block-pairs
    const int nbpb = nblk / out_size;            // 32 blocks per batch

    hipMemsetAsync(out, 0, (size_t)out_size * sizeof(float), stream);
    dtw_k<<<nblk, 64, 0, stream>>>(x, y, out, nbpb);
}

// Round 14
// 41.932 us; speedup vs baseline: 1.5171x; 1.0960x over previous
//
#include <hip/hip_runtime.h>

#define NB    128           // DTW block size N
#define NCH   64            // channels
#define ROWB  256           // bytes per sD row: 128 h16
#define LOG2E 1.4426950408889634f
#define LN2   0.6931471805599453f
#define LARGE 1e9f

typedef _Float16 h16;
typedef __attribute__((ext_vector_type(2))) _Float16 h16x2;
typedef __attribute__((ext_vector_type(8))) _Float16 h16x8;
typedef __attribute__((ext_vector_type(4))) float    f32x4;

static __device__ __forceinline__ float ex2(float x) {
#if __has_builtin(__builtin_amdgcn_exp2f)
    return __builtin_amdgcn_exp2f(x);
#else
    return exp2f(x);
#endif
}

static __device__ __forceinline__ float lg2(float x) {
#if __has_builtin(__builtin_amdgcn_logf)
    return __builtin_amdgcn_logf(x);   // v_log_f32 = log2
#else
    return log2f(x);
#endif
}

// lane t gets lane t-1's src; lane 0 gets `fill`. Pure VALU (DPP wave_shr:1).
static __device__ __forceinline__ float shift_up1(float src, float fill) {
    int r = __builtin_amdgcn_update_dpp(__builtin_bit_cast(int, fill),
                                        __builtin_bit_cast(int, src),
                                        0x138 /*wave_shr:1*/, 0xf, 0xf, false);
    return __builtin_bit_cast(float, r);
}

// soft-min of 3 in log2 domain + D*log2e (gamma=1, exact w.r.t. reference).
static __device__ __forceinline__ float softmin3(float a, float b, float c, float Dv) {
    float m = fminf(fminf(a, b), c);
    float M = fmaxf(fmaxf(a, b), c);
#if __has_builtin(__builtin_amdgcn_fmed3f)
    float e = __builtin_amdgcn_fmed3f(a, b, c);
#else
    float e = ((a + b) + c) - m - M;
#endif
    float s = 1.0f + (ex2(m - e) + ex2(m - M));
    return fmaf(Dv, LOG2E, m - lg2(s));
}

__global__ __launch_bounds__(64, 1)
void dtw_k(const float* __restrict__ X, const float* __restrict__ Y,
           float* __restrict__ out, int nbpb)
{
    __shared__ h16 sD[NB * (ROWB / 2)];     // 32768 B

    const int w = blockIdx.x;               // block-pair id
    const int t = threadIdx.x;              // 0..63
    const int c = t & 15, g = t >> 4;       // MFMA fragment coords
    char* sDb = (char*)sD;
    const float* gx = X + (size_t)w * (NB * NCH);
    const float* gy = Y + (size_t)w * (NB * NCH);

    // ---- B fragments (y rows as MFMA B operand) + y2 norms, all in registers.
    h16x8 Bf[8][2];
    float y2r[8];
    #pragma unroll
    for (int J = 0; J < 8; ++J) {
        const float* py = gy + (16 * J + c) * NCH + 8 * g;
        float p = 0.f;
        #pragma unroll
        for (int q = 0; q < 2; ++q) {
            float4 a = *(const float4*)(py + 32 * q);
            float4 b = *(const float4*)(py + 32 * q + 4);
            h16x8 h;
            h[0]=(h16)a.x; h[1]=(h16)a.y; h[2]=(h16)a.z; h[3]=(h16)a.w;
            h[4]=(h16)b.x; h[5]=(h16)b.y; h[6]=(h16)b.z; h[7]=(h16)b.w;
            Bf[J][q] = h;
            p = fmaf(a.x,a.x,p); p = fmaf(a.y,a.y,p);
            p = fmaf(a.z,a.z,p); p = fmaf(a.w,a.w,p);
            p = fmaf(b.x,b.x,p); p = fmaf(b.y,b.y,p);
            p = fmaf(b.z,b.z,p); p = fmaf(b.w,b.w,p);
        }
        p += __shfl_xor(p, 16, 64);
        p += __shfl_xor(p, 32, 64);
        y2r[J] = p;                          // ||y[16J+c]||^2
    }

    // ---- build phase: all 8 row-tiles (A prefetched one tile ahead).
    // Writes EVERY byte of sD (rows 16I+4g+r, all 128 cols) before DP starts.
    float4 nx0, nx1, nx2, nx3;
    {
        const float* px = gx + c * NCH + 8 * g;
        nx0 = *(const float4*)(px);
        nx1 = *(const float4*)(px + 4);
        nx2 = *(const float4*)(px + 32);
        nx3 = *(const float4*)(px + 36);
    }
    for (int I = 0; I < 8; ++I) {
        float4 a0 = nx0, a1 = nx1, a2 = nx2, a3 = nx3;
        if (I < 7) {
            const float* px = gx + (16 * (I + 1) + c) * NCH + 8 * g;
            nx0 = *(const float4*)(px);
            nx1 = *(const float4*)(px + 4);
            nx2 = *(const float4*)(px + 32);
            nx3 = *(const float4*)(px + 36);
        }
        h16x8 Af0, Af1;
        Af0[0]=(h16)a0.x; Af0[1]=(h16)a0.y; Af0[2]=(h16)a0.z; Af0[3]=(h16)a0.w;
        Af0[4]=(h16)a1.x; Af0[5]=(h16)a1.y; Af0[6]=(h16)a1.z; Af0[7]=(h16)a1.w;
        Af1[0]=(h16)a2.x; Af1[1]=(h16)a2.y; Af1[2]=(h16)a2.z; Af1[3]=(h16)a2.w;
        Af1[4]=(h16)a3.x; Af1[5]=(h16)a3.y; Af1[6]=(h16)a3.z; Af1[7]=(h16)a3.w;
        float p = 0.f;
        p=fmaf(a0.x,a0.x,p); p=fmaf(a0.y,a0.y,p); p=fmaf(a0.z,a0.z,p); p=fmaf(a0.w,a0.w,p);
        p=fmaf(a1.x,a1.x,p); p=fmaf(a1.y,a1.y,p); p=fmaf(a1.z,a1.z,p); p=fmaf(a1.w,a1.w,p);
        p=fmaf(a2.x,a2.x,p); p=fmaf(a2.y,a2.y,p); p=fmaf(a2.z,a2.z,p); p=fmaf(a2.w,a2.w,p);
        p=fmaf(a3.x,a3.x,p); p=fmaf(a3.y,a3.y,p); p=fmaf(a3.z,a3.z,p); p=fmaf(a3.w,a3.w,p);
        p += __shfl_xor(p, 16, 64);
        p += __shfl_xor(p, 32, 64);
        float xa[4];
        xa[0] = __shfl(p, 4 * g + 0, 64);
        xa[1] = __shfl(p, 4 * g + 1, 64);
        xa[2] = __shfl(p, 4 * g + 2, 64);
        xa[3] = __shfl(p, 4 * g + 3, 64);

        f32x4 acc[8];
        #pragma unroll
        for (int J = 0; J < 8; ++J) {
            f32x4 z = {0.f, 0.f, 0.f, 0.f};
            z = __builtin_amdgcn_mfma_f32_16x16x32_f16(Af0, Bf[J][0], z, 0, 0, 0);
            z = __builtin_amdgcn_mfma_f32_16x16x32_f16(Af1, Bf[J][1], z, 0, 0, 0);
            acc[J] = z;
        }
        #pragma unroll
        for (int J = 0; J < 8; ++J) {
            char* base = sDb + 2 * (16 * J + c) + ROWB * (16 * I + 4 * g);
            float y2v = y2r[J];
            #pragma unroll
            for (int r = 0; r < 4; ++r) {
                float dv = fmaf(-2.0f, acc[J][r], xa[r] + y2v);
                *(h16*)(base + ROWB * r) = (h16)dv;
            }
        }
    }

    // ---- DP phase (pure): lane t owns rows 2t/2t+1; negative-offset window.
    // Triple-buffered chunk regs, prefetch 2 chunks (32 steps) ahead:
    // DS latency is provably covered by >2000 cycles of issue distance.
    const int baseA = 508 * t;          // row 2t byte base (512t) minus 4t
    const int baseB = 508 * t + 256;

    h16x2 bA0[8], bB0[8], bA1[8], bB1[8], bA2[8], bB2[8];
    #define LOAD8(dst, off) { \
        const h16x2* p_ = (const h16x2*)(sDb + (off)); \
        _Pragma("unroll") for (int q = 0; q < 8; ++q) (dst)[q] = p_[q]; }

    LOAD8(bA0, baseA)        LOAD8(bB0, baseB)
    LOAD8(bA1, baseA + 32)   LOAD8(bB1, baseB + 32)

    float fA[16], fB[16];
    float r1a = LARGE, r1b = LARGE, r2a = LARGE;
    float dg_prev = (t == 0) ? 0.0f : LARGE;   // corner R[-1][-1]=0 feeds cell (0,0)
    float carryB = 0.0f;

    #define CONVERT(sa, sb) { _Pragma("unroll") for (int q = 0; q < 8; ++q) { \
        fA[2*q] = (float)(sa)[q][0]; fA[2*q+1] = (float)(sa)[q][1]; \
        fB[2*q] = (float)(sb)[q][0]; fB[2*q+1] = (float)(sb)[q][1]; } }

    #define STEP(D0v, D1v) { \
        float up_cur = shift_up1(r1b, LARGE); \
        float n0 = softmin3(r1a, up_cur, dg_prev, (D0v)); \
        float n1 = softmin3(r1b, r1a, r2a, (D1v)); \
        r2a = r1a; r1a = n0; r1b = n1; dg_prev = up_cur; }

    // CHUNK(cc, cur-set, prefetch-set): consume chunk cc, load chunk cc+2.
    #define CHUNK(ccv, curA, curB, pfA, pfB) { \
        CONVERT(curA, curB) \
        if ((ccv) + 2 < 16) { \
            LOAD8(pfA, baseA + 32 * ((ccv) + 2)) \
            LOAD8(pfB, baseB + 32 * ((ccv) + 2)) \
        } \
        const int kmax_ = ((ccv) == 15) ? 15 : 16; \
        _Pragma("unroll") \
        for (int k = 0; k < 16; ++k) { \
            if (k < kmax_) { \
                float D1v = (k == 0) ? carryB : fB[k - 1]; \
                STEP(fA[k], D1v) \
            } \
        } \
        carryB = fB[15]; }

    CHUNK( 0, bA0, bB0, bA2, bB2)
    CHUNK( 1, bA1, bB1, bA0, bB0)
    CHUNK( 2, bA2, bB2, bA1, bB1)
    CHUNK( 3, bA0, bB0, bA2, bB2)
    CHUNK( 4, bA1, bB1, bA0, bB0)
    CHUNK( 5, bA2, bB2, bA1, bB1)
    CHUNK( 6, bA0, bB0, bA2, bB2)
    CHUNK( 7, bA1, bB1, bA0, bB0)
    CHUNK( 8, bA2, bB2, bA1, bB1)
    CHUNK( 9, bA0, bB0, bA2, bB2)
    CHUNK(10, bA1, bB1, bA0, bB0)
    CHUNK(11, bA2, bB2, bA1, bB1)
    CHUNK(12, bA0, bB0, bA2, bB2)
    CHUNK(13, bA1, bB1, bA0, bB0)
    CHUNK(14, bA2, bB2, bA1, bB1)
    CHUNK(15, bA0, bB0, bA2, bB2)

    if (t == 63) {
        atomicAdd(&out[w / nbpb], r1b * LN2);   // back to natural-log domain
    }
}

extern "C" void kernel_launch(void* const* d_in, const int* in_sizes, int n_in,
                              void* d_out, int out_size, void* d_ws, size_t ws_size,
                              hipStream_t stream) {
    const float* x = (const float*)d_in[0];
    const float* y = (const float*)d_in[1];
    float* out = (float*)d_out;

    const int nblk = in_sizes[0] / (NB * NCH);   // 1024 block-pairs
    const int nbpb = nblk / out_size;            // 32 blocks per batch

    hipMemsetAsync(out, 0, (size_t)out_size * sizeof(float), stream);
    dtw_k<<<nblk, 64, 0, stream>>>(x, y, out, nbpb);
}